// Round 10
// baseline (431617.676 us; speedup 1.0000x reference)
//
#include <hip/hip_runtime.h>
#include <math.h>

// ODE-RNN, T=8192, IN=512, H=1024, OUT=256, 4 euler substeps/step.
// R10: deadlock-proofed XCD-local dataflow cluster.
//   Agent-scope handoffs measured ~2us/phase across R4-R8 (the device
//   coherence point is beyond the per-XCD L2). If 32 worker WGs share ONE
//   XCD, its 4MB L2 is their coherence point: sc0 store (write-through L1
//   -> local L2) + sc0 poll load (L1-bypass, L2-serviced) = sub-us handoff.
// Deadlock-proofing (R9 hung):
//   a) publish store now carries sc0 (R9's flagless store could linger
//      above L2 while pollers spun on L2 -> permanent stall).
//   b) bounded election spin; on timeout chosen:=8 -> fallback workers
//      (blockIdx<32) run the PROVEN agent-scope protocol.
//   c) 2-round hardware self-test of the local-mode primitives through a
//      scratch queue (bounded polls, >=-tag compare), then agent-scope
//      barrier+agreement commits ONE mode uniformly. Same-XCD => shared L2
//      => test-pass implies structural coherence; else agent mode.
// Recurrence (validated R4-R8, absmax 0):
//   z = W_f1 h + b_f1, M = W_f1 W_f2, P = W_h W_f2 (precomputed GEMMs)
//   4x substep: publish u=tanh(z); z += dt(M u + c1)     [M-dot, registers]
//   y4 = W_h h + dt*P*(u1+..+u4) + 4 dt c2               [one P-dot/step]
//   a = tanh(y4 + W_in x + b); h' = tanh(W_h2 a + b_h2)  [W_h2 from LDS]
//   z reset from h' each step (no factorization error accumulation).
// Handoff: epoch-tagged 8B words (tag<<32|f32). WAR-safe: full-read ring.

#define TSTEPS 8192
#define INP    512
#define HDIM   1024
#define GRID   256
#define BLK    256
#define NWRK   32
#define RPW    32          // rows per worker
#define SEGN   8           // threads per row
#define F4PT   32          // float4 per thread per H-row (1024/8/4)

typedef unsigned long long u64;
typedef unsigned int u32;

__device__ __forceinline__ u64 aload(u64* p) {
    return __hip_atomic_load(p, __ATOMIC_RELAXED, __HIP_MEMORY_SCOPE_AGENT);
}
__device__ __forceinline__ void astore(u64* p, u64 v) {
    __hip_atomic_store(p, v, __ATOMIC_RELAXED, __HIP_MEMORY_SCOPE_AGENT);
}
__device__ __forceinline__ u64 pack(u32 tag, float f) {
    return ((u64)tag << 32) | (u64)__float_as_uint(f);
}

// XCD-local primitives: sc0 = L1-bypass/write-through, serviced at XCD L2.
__device__ __forceinline__ void sePoll4(const u64* p0, const u64* p1,
                                        const u64* p2, const u64* p3,
                                        u64& v0, u64& v1, u64& v2, u64& v3) {
    asm volatile(
        "global_load_dwordx2 %0, %4, off sc0\n\t"
        "global_load_dwordx2 %1, %5, off sc0\n\t"
        "global_load_dwordx2 %2, %6, off sc0\n\t"
        "global_load_dwordx2 %3, %7, off sc0\n\t"
        "s_waitcnt vmcnt(0)"
        : "=&v"(v0), "=&v"(v1), "=&v"(v2), "=&v"(v3)
        : "v"(p0), "v"(p1), "v"(p2), "v"(p3)
        : "memory");
}
__device__ __forceinline__ void seStore(u64* p, u64 v) {
    asm volatile("global_store_dwordx2 %0, %1, off sc0"
                 :: "v"(p), "v"(v) : "memory");
}

// ---------------- precompute: C = A @ B, 1024x1024x1024 fp32 ----------------
__global__ __launch_bounds__(256)
void mm1024(const float* __restrict__ A, const float* __restrict__ B,
            float* __restrict__ C) {
    __shared__ float As[64][17];
    __shared__ float Bs[16][65];
    const int tid = threadIdx.x;
    const int tx = tid & 15, ty = tid >> 4;
    const int r0 = blockIdx.y * 64, c0 = blockIdx.x * 64;
    float acc[4][4] = {};
    for (int k0 = 0; k0 < HDIM; k0 += 16) {
        const int ar = tid >> 2, ac = (tid & 3) * 4;
        const float4 av = *reinterpret_cast<const float4*>(
            A + (size_t)(r0 + ar) * HDIM + k0 + ac);
        As[ar][ac] = av.x; As[ar][ac + 1] = av.y;
        As[ar][ac + 2] = av.z; As[ar][ac + 3] = av.w;
        const int br = tid >> 4, bc = (tid & 15) * 4;
        const float4 bv = *reinterpret_cast<const float4*>(
            B + (size_t)(k0 + br) * HDIM + c0 + bc);
        Bs[br][bc] = bv.x; Bs[br][bc + 1] = bv.y;
        Bs[br][bc + 2] = bv.z; Bs[br][bc + 3] = bv.w;
        __syncthreads();
        #pragma unroll
        for (int kk = 0; kk < 16; ++kk) {
            float a[4], b[4];
            #pragma unroll
            for (int i2 = 0; i2 < 4; ++i2) a[i2] = As[ty * 4 + i2][kk];
            #pragma unroll
            for (int j2 = 0; j2 < 4; ++j2) b[j2] = Bs[kk][tx * 4 + j2];
            #pragma unroll
            for (int i2 = 0; i2 < 4; ++i2)
                #pragma unroll
                for (int j2 = 0; j2 < 4; ++j2)
                    acc[i2][j2] = fmaf(a[i2], b[j2], acc[i2][j2]);
        }
        __syncthreads();
    }
    #pragma unroll
    for (int i2 = 0; i2 < 4; ++i2)
        #pragma unroll
        for (int j2 = 0; j2 < 4; ++j2)
            C[(size_t)(r0 + ty * 4 + i2) * HDIM + c0 + tx * 4 + j2] = acc[i2][j2];
}

// ---------------------------- persistent kernel -----------------------------
__global__ __launch_bounds__(BLK, 1)
void ode_rnn_xcd(
    const float* __restrict__ t,    const float* __restrict__ x,
    const float* __restrict__ W_in, const float* __restrict__ b_in,
    const float* __restrict__ W_h,  const float* __restrict__ b_h,
    const float* __restrict__ W_h2, const float* __restrict__ b_h2,
    const float* __restrict__ W_f1, const float* __restrict__ b_f1,
    const float* __restrict__ b_f2,
    const float* __restrict__ W_dec, const float* __restrict__ b_dec,
    const float* __restrict__ Mw,   const float* __restrict__ Pw,
    float* __restrict__ out,
    u64* QA, u64* QB, u64* QC, u64* QD, u64* QT,
    int* cnt, int* fail_cnt, int* barc, int* chosen)
{
    extern __shared__ float smem[];
    float* wh2l = smem;                    // [32][1024] own W_h2 rows (128KB)
    float* sb0  = smem + RPW * HDIM;       // 3 rotating stage buffers
    float* sb1  = sb0 + HDIM;
    float* sb2  = sb1 + HDIM;
    float* us   = sb2 + HDIM;              // usum accumulator
    float* xb   = us + HDIM;               // staged x row (512)

    __shared__ int s_role, s_cand, s_ok[4];
    const int tid = threadIdx.x;

    // ---- bounded XCD-cluster election (deadlock-free) ----
    if (tid == 0) {
        u32 xcc;
        asm volatile("s_getreg_b32 %0, hwreg(HW_REG_XCC_ID)" : "=s"(xcc));
        xcc &= 7;
        const int slot = atomicAdd(&cnt[xcc], 1);        // device-scope
        if (slot == NWRK - 1) atomicCAS(chosen, -1, (int)xcc);
        int c = -1;
        for (int it = 0; it < (1 << 20); ++it) {
            c = __hip_atomic_load(chosen, __ATOMIC_RELAXED,
                                  __HIP_MEMORY_SCOPE_AGENT);
            if (c != -1) break;
        }
        if (c == -1) {                     // election stalled: force fallback
            atomicCAS(chosen, -1, 8);
            do {
                c = __hip_atomic_load(chosen, __ATOMIC_RELAXED,
                                      __HIP_MEMORY_SCOPE_AGENT);
            } while (c == -1);
        }
        if (c == 8) { s_role = (blockIdx.x < NWRK) ? (int)blockIdx.x : -1; s_cand = 0; }
        else        { s_role = (c == (int)xcc && slot < NWRK) ? slot : -1;  s_cand = 1; }
    }
    __syncthreads();
    const int  w    = s_role;
    const bool cand = (s_cand != 0);
    if (w < 0) return;                     // not in the cluster

    const int seg  = tid & (SEGN - 1);     // 0..7 within a row group
    const int rloc = tid >> 3;             // local row 0..31
    const int row  = w * RPW + rloc;       // owned global row

    // ---- self-test of XCD-local primitives, then uniform mode agreement ----
    bool lm = false;
    if (cand) {
        int okl = 1;
        for (u32 tr = 1; tr <= 2; ++tr) {
            if (okl) {
                if (seg == 0) seStore(&QT[row], pack(tr, 1.0f));
                u64 *q0 = QT + tid, *q1 = QT + tid + 256,
                    *q2 = QT + tid + 512, *q3 = QT + tid + 768;
                int sweeps = 0;
                for (;;) {
                    u64 v0, v1, v2, v3;
                    sePoll4(q0, q1, q2, q3, v0, v1, v2, v3);
                    const bool ok =
                        ((u32)(v0 >> 32) >= tr) & ((u32)(v1 >> 32) >= tr) &
                        ((u32)(v2 >> 32) >= tr) & ((u32)(v3 >> 32) >= tr);
                    if (__all(ok)) break;            // >=: test tags ungated
                    if (++sweeps > (1 << 16)) { okl = 0; break; }
                }
            }
        }
        if ((tid & 63) == 0) s_ok[tid >> 6] = okl;
        __syncthreads();
        if (tid == 0) {
            const int o = s_ok[0] & s_ok[1] & s_ok[2] & s_ok[3];
            if (!o) atomicAdd(fail_cnt, 1);
            __threadfence();
            atomicAdd(barc, 1);                       // agent barrier (proven)
            int b;
            do {
                b = __hip_atomic_load(barc, __ATOMIC_RELAXED,
                                      __HIP_MEMORY_SCOPE_AGENT);
            } while (b < NWRK);
            __threadfence();
            s_cand = (__hip_atomic_load(fail_cnt, __ATOMIC_RELAXED,
                                        __HIP_MEMORY_SCOPE_AGENT) == 0) ? 1 : 0;
        }
        __syncthreads();
        lm = (s_cand != 0);                // uniform across all 32 workers
    }

    // ---- LDS: own 32 rows of W_h2 ----
    {
        const float4* src = reinterpret_cast<const float4*>(
            W_h2 + (size_t)w * RPW * HDIM);
        float4* dst = reinterpret_cast<float4*>(wh2l);
        for (int k = tid; k < RPW * HDIM / 4; k += BLK) dst[k] = src[k];
    }

    // ---- registers: own M,P rows (zero mem ops in substep critical path) ----
    float4 m32[F4PT], p32[F4PT];
    {
        const float4* pM = reinterpret_cast<const float4*>(Mw + (size_t)row * HDIM);
        const float4* pP = reinterpret_cast<const float4*>(Pw + (size_t)row * HDIM);
        #pragma unroll
        for (int j = 0; j < F4PT; ++j) {
            m32[j] = pM[j * SEGN + seg];
            p32[j] = pP[j * SEGN + seg];
        }
    }

    const float bf1_r = b_f1[row];
    const float bih_r = b_in[row] + b_h[row];
    const float bh2_r = b_h2[row];

    auto red8 = [&](float a) {             // butterfly: all 8 lanes get sum
        #pragma unroll
        for (int off = 4; off; off >>= 1) a += __shfl_xor(a, off, SEGN);
        return a;
    };
    auto dotReg = [&](const float4 (&wr)[F4PT], const float* v) {
        float a = 0.f;
        #pragma unroll
        for (int j = 0; j < F4PT; ++j) {
            const float4 vv = *reinterpret_cast<const float4*>(
                v + (j * SEGN + seg) * 4);
            a = fmaf(wr[j].x, vv.x, a); a = fmaf(wr[j].y, vv.y, a);
            a = fmaf(wr[j].z, vv.z, a); a = fmaf(wr[j].w, vv.w, a);
        }
        return red8(a);
    };
    auto dotLdsW = [&](const float* v) {   // W_h2 panel dot (LDS weights)
        const float* wr = wh2l + rloc * HDIM;
        float a = 0.f;
        #pragma unroll
        for (int j = 0; j < F4PT; ++j) {
            const int e = (j * SEGN + seg) * 4;
            const float4 wv = *reinterpret_cast<const float4*>(wr + e);
            const float4 vv = *reinterpret_cast<const float4*>(v + e);
            a = fmaf(wv.x, vv.x, a); a = fmaf(wv.y, vv.y, a);
            a = fmaf(wv.z, vv.z, a); a = fmaf(wv.w, vv.w, a);
        }
        return red8(a);
    };
    auto dotStreamPart = [&](const float* Wb, const float* v, int c0, int c1,
                             float a) {
        const float4* wp = reinterpret_cast<const float4*>(Wb + (size_t)row * HDIM);
        for (int c = c0; c < c1; c += 8) {
            float4 wreg[8];
            #pragma unroll
            for (int j = 0; j < 8; ++j) wreg[j] = wp[(c + j) * SEGN + seg];
            #pragma unroll
            for (int j = 0; j < 8; ++j) {
                const float4 vv = *reinterpret_cast<const float4*>(
                    v + ((c + j) * SEGN + seg) * 4);
                a = fmaf(wreg[j].x, vv.x, a); a = fmaf(wreg[j].y, vv.y, a);
                a = fmaf(wreg[j].z, vv.z, a); a = fmaf(wreg[j].w, vv.w, a);
            }
        }
        return a;
    };
    auto prefRow = [&](const float* Wb, int c0) {   // warm own row into L2/L1
        const float4* wp = reinterpret_cast<const float4*>(Wb + (size_t)row * HDIM);
        #pragma unroll
        for (int j = 0; j < 16; ++j) {
            const float4 wv = wp[(c0 + j) * SEGN + seg];
            asm volatile("" :: "v"(wv.x), "v"(wv.y), "v"(wv.z), "v"(wv.w));
        }
    };
    auto dotWinx = [&]() {                 // W_in (streamed) @ x (LDS)
        const float4* wp = reinterpret_cast<const float4*>(W_in + (size_t)row * INP);
        float a = 0.f;
        #pragma unroll
        for (int j = 0; j < 16; ++j) {
            const float4 wv = wp[j * SEGN + seg];
            const float4 vv = *reinterpret_cast<const float4*>(
                xb + (j * SEGN + seg) * 4);
            a = fmaf(wv.x, vv.x, a); a = fmaf(wv.y, vv.y, a);
            a = fmaf(wv.z, vv.z, a); a = fmaf(wv.w, vv.w, a);
        }
        return red8(a);
    };
    auto pub = [&](u64* q, u32 e, float pre) {
        if (seg == 0) {
            const u64 pv = pack(e, tanhf(pre));
            if (lm) seStore(&q[row], pv);
            else    astore(&q[row], pv);
        }
    };

    int pb = 0;
    auto stage = [&](u64* q, u32 tag, int mode) -> float* {
        float* dst = (pb == 0) ? sb0 : (pb == 1) ? sb1 : sb2;
        pb = (pb == 2) ? 0 : pb + 1;
        u64 *q0 = q + tid, *q1 = q + tid + 256, *q2 = q + tid + 512,
            *q3 = q + tid + 768;
        u64 v0, v1, v2, v3;
        if (lm) {
            for (;;) {
                sePoll4(q0, q1, q2, q3, v0, v1, v2, v3);
                const bool ok =
                    ((u32)(v0 >> 32) == tag) & ((u32)(v1 >> 32) == tag) &
                    ((u32)(v2 >> 32) == tag) & ((u32)(v3 >> 32) == tag);
                if (__all(ok)) break;
            }
        } else {
            for (;;) {
                v0 = aload(q0); v1 = aload(q1); v2 = aload(q2); v3 = aload(q3);
                const bool ok =
                    ((u32)(v0 >> 32) == tag) & ((u32)(v1 >> 32) == tag) &
                    ((u32)(v2 >> 32) == tag) & ((u32)(v3 >> 32) == tag);
                if (ok) break;
            }
        }
        const float f0 = __uint_as_float((u32)v0), f1 = __uint_as_float((u32)v1);
        const float f2 = __uint_as_float((u32)v2), f3 = __uint_as_float((u32)v3);
        dst[tid] = f0; dst[tid + 256] = f1; dst[tid + 512] = f2; dst[tid + 768] = f3;
        if (mode == 1) {
            us[tid] = f0; us[tid + 256] = f1; us[tid + 512] = f2; us[tid + 768] = f3;
        } else if (mode == 2) {
            us[tid] += f0; us[tid + 256] += f1; us[tid + 512] += f2; us[tid + 768] += f3;
        }
        __syncthreads();
        return dst;
    };

    // ---- init: c1=(W_f1 b_f2)[row], c2=(W_h b_f2)[row]; x[1] into LDS ----
    __syncthreads();                       // W_h2 panel ready
    for (int k = tid; k < HDIM; k += BLK) sb0[k] = b_f2[k];
    reinterpret_cast<float2*>(xb)[tid] =
        reinterpret_cast<const float2*>(x + (size_t)1 * INP)[tid];
    __syncthreads();
    const float c1_own = red8(dotStreamPart(W_f1, sb0, 0, 32, 0.f));
    const float c2_own = red8(dotStreamPart(W_h,  sb0, 0, 32, 0.f));
    __syncthreads();                       // sb0 free for stage rotation

    float z_own = bf1_r;                   // z1 = W_f1*0 + b_f1
    u32 eA = 0, eB = 0, eC = 0, eD = 0;
    float* hbuf = sb0;

    #pragma unroll 1
    for (int i = 1; i < TSTEPS; ++i) {
        const float dt = (t[i] - t[i - 1]) * 0.25f;

        // ph1 (u1 -> QA); gap: first half of deferred yd = W_h h_{i-1}
        ++eA;
        pub(QA, eA, z_own);
        float ydacc = 0.f;
        if (i > 1) ydacc = dotStreamPart(W_h, hbuf, 0, 16, 0.f);
        float* b1 = stage(QA, eA, 1);
        z_own = fmaf(dt, dotReg(m32, b1) + c1_own, z_own);

        // ph2 (u2 -> QB); gap: second half of yd
        ++eB;
        pub(QB, eB, z_own);
        if (i > 1) ydacc = dotStreamPart(W_h, hbuf, 16, 32, ydacc);
        const float yd = red8(ydacc);
        float* b2 = stage(QB, eB, 2);
        z_own = fmaf(dt, dotReg(m32, b2) + c1_own, z_own);

        // ph3 (u3 -> QA); gap: warm first half of own W_f1 row
        ++eA;
        pub(QA, eA, z_own);
        prefRow(W_f1, 0);
        float* b3 = stage(QA, eA, 2);
        z_own = fmaf(dt, dotReg(m32, b3) + c1_own, z_own);

        // ph4 (u4 -> QB); gap: winx; then ONE register P-dot on usum
        ++eB;
        pub(QB, eB, z_own);
        const float winx = dotWinx();
        stage(QB, eB, 2);
        const float pd = dotReg(p32, us);
        const float apre = fmaf(dt, pd + 4.f * c2_own, yd) + winx + bih_r;

        // ph5 (a -> QC); gap: warm second half of W_f1; h' = tanh(W_h2 a + b)
        ++eC;
        pub(QC, eC, apre);
        prefRow(W_f1, 16);
        float* b5 = stage(QC, eC, 0);
        const float hpre = dotLdsW(b5) + bh2_r;

        // ph6 (h' -> QD); gap: stage next x row; z' = W_f1 h' (warm stream)
        ++eD;
        pub(QD, eD, hpre);
        if (i + 1 < TSTEPS)
            reinterpret_cast<float2*>(xb)[tid] =
                reinterpret_cast<const float2*>(x + (size_t)(i + 1) * INP)[tid];
        float* b6 = stage(QD, eD, 0);
        hbuf = b6;
        z_own = red8(dotStreamPart(W_f1, b6, 0, 32, 0.f)) + bf1_r;
    }

    // ---- decoder: 8 output rows per worker; h_T is in hbuf ----
    {
        const int rl = tid >> 5, s2 = tid & 31;
        const int orow = w * 8 + rl;
        const float4* wd = reinterpret_cast<const float4*>(
            W_dec + (size_t)orow * HDIM);
        float acc = 0.f;
        #pragma unroll
        for (int j = 0; j < 8; ++j) {
            const float4 wv = wd[j * 32 + s2];
            const float4 vv = *reinterpret_cast<const float4*>(
                hbuf + (j * 32 + s2) * 4);
            acc = fmaf(wv.x, vv.x, acc); acc = fmaf(wv.y, vv.y, acc);
            acc = fmaf(wv.z, vv.z, acc); acc = fmaf(wv.w, vv.w, acc);
        }
        #pragma unroll
        for (int off = 16; off; off >>= 1) acc += __shfl_xor(acc, off, 32);
        if (s2 == 0) out[orow] = acc + b_dec[orow];
    }
}

extern "C" void kernel_launch(void* const* d_in, const int* in_sizes, int n_in,
                              void* d_out, int out_size, void* d_ws, size_t ws_size,
                              hipStream_t stream) {
    const float* t     = (const float*)d_in[0];
    const float* x     = (const float*)d_in[1];
    const float* W_in  = (const float*)d_in[2];
    const float* b_in  = (const float*)d_in[3];
    const float* W_h   = (const float*)d_in[4];
    const float* b_h   = (const float*)d_in[5];
    const float* W_h2  = (const float*)d_in[6];
    const float* b_h2  = (const float*)d_in[7];
    const float* W_f1  = (const float*)d_in[8];
    const float* b_f1  = (const float*)d_in[9];
    const float* W_f2  = (const float*)d_in[10];
    const float* b_f2  = (const float*)d_in[11];
    const float* W_dec = (const float*)d_in[12];
    const float* b_dec = (const float*)d_in[13];
    float* out = (float*)d_out;

    // ws: M(4MB) | P(4MB) | QA QB QC QD QT (5x8KB) | cnt[8] fail bar chosen
    unsigned char* ws = (unsigned char*)d_ws;
    float* Mw = (float*)(ws);
    float* Pw = (float*)(ws + (size_t)4 * 1024 * 1024);
    u64*   QA = (u64*)(ws + (size_t)8 * 1024 * 1024);
    u64*   QB = QA + HDIM;
    u64*   QC = QB + HDIM;
    u64*   QD = QC + HDIM;
    u64*   QT = QD + HDIM;
    int*   cnt      = (int*)(QT + HDIM);
    int*   fail_cnt = cnt + 8;
    int*   barc     = cnt + 9;
    int*   chosen   = cnt + 10;

    // precompute M = W_f1 @ W_f2, P = W_h @ W_f2 (every call; deterministic)
    mm1024<<<dim3(16, 16), 256, 0, stream>>>(W_f1, W_f2, Mw);
    mm1024<<<dim3(16, 16), 256, 0, stream>>>(W_h,  W_f2, Pw);

    // zero tags + election/agreement words; chosen = -1. Every call.
    hipMemsetAsync(ws + (size_t)8 * 1024 * 1024, 0,
                   (size_t)5 * HDIM * sizeof(u64) + 10 * sizeof(int), stream);
    hipMemsetAsync(chosen, 0xFF, sizeof(int), stream);

    // dynamic LDS: W_h2 panel (128KB) + 3 stage bufs + usum + x = ~146KB
    // -> 1 WG/CU -> all 256 WGs co-resident -> election pigeonhole.
    const size_t smem_bytes =
        (size_t)(RPW * HDIM + 3 * HDIM + HDIM + INP) * sizeof(float);
    ode_rnn_xcd<<<dim3(GRID), dim3(BLK), smem_bytes, stream>>>(
        t, x, W_in, b_in, W_h, b_h, W_h2, b_h2, W_f1, b_f1, b_f2,
        W_dec, b_dec, Mw, Pw, out, QA, QB, QC, QD, QT,
        cnt, fail_cnt, barc, chosen);
}

// Round 12
// 100398.236 us; speedup vs baseline: 4.2991x; 4.2991x over previous
//
#include <hip/hip_runtime.h>
#include <math.h>

// ODE-RNN, T=8192, IN=512, H=1024, OUT=256, 4 euler substeps/step.
// R12 = the measured-best round-5 kernel (100.5 ms), restored token-for-token.
//   (R11's "restore" dropped the tanh on the phase-5/6 publishes -> unstable
//    linear recurrence -> NaN. This is the literal round-5 source.)
//   z = W_f1 h + b_f1,  y = W_h h,  M = W_f1 W_f2,  P = W_h W_f2 (precomputed)
//   substep: u = tanh(z); z += dt(M u + c1); y += dt(P u + c2)   [1 broadcast]
//   cell:    a = tanh(y4 + W_in x + b_in + b_h)                  [1 broadcast]
//            h' = tanh(W_h2 a + b_h2)                            [1 broadcast]
//   z,y reset from h' each step (no factorization error accumulation).
// Handoff = epoch-tagged 8B agent atomics (tag<<32 | f32). Concurrent 4-slot
// poll; weight rows register-prefetched before the poll (hidden under spin).
// WAR-safe: every queue has reuse distance >= 2 full-broadcast consumptions
// (u alternates QA/QB), so a slot can't advance past a waiting reader.

#define TSTEPS 8192
#define INP    512
#define HDIM   1024
#define OUTD   256
#define NWG    64
#define BLK    256

typedef unsigned long long u64;
typedef unsigned int u32;

__device__ __forceinline__ u64 aload(u64* p) {
    return __hip_atomic_load(p, __ATOMIC_RELAXED, __HIP_MEMORY_SCOPE_AGENT);
}
__device__ __forceinline__ void astore(u64* p, u64 v) {
    __hip_atomic_store(p, v, __ATOMIC_RELAXED, __HIP_MEMORY_SCOPE_AGENT);
}
__device__ __forceinline__ u64 pack(u32 tag, float f) {
    return ((u64)tag << 32) | (u64)__float_as_uint(f);
}

// ---------------- precompute: C = A @ B, 1024x1024x1024 fp32 ----------------
__global__ __launch_bounds__(256)
void mm1024(const float* __restrict__ A, const float* __restrict__ B,
            float* __restrict__ C) {
    __shared__ float As[64][17];
    __shared__ float Bs[16][65];
    const int tid = threadIdx.x;
    const int tx = tid & 15, ty = tid >> 4;
    const int r0 = blockIdx.y * 64, c0 = blockIdx.x * 64;
    float acc[4][4] = {};
    for (int k0 = 0; k0 < HDIM; k0 += 16) {
        const int ar = tid >> 2, ac = (tid & 3) * 4;
        const float4 av = *reinterpret_cast<const float4*>(
            A + (size_t)(r0 + ar) * HDIM + k0 + ac);
        As[ar][ac] = av.x; As[ar][ac + 1] = av.y;
        As[ar][ac + 2] = av.z; As[ar][ac + 3] = av.w;
        const int br = tid >> 4, bc = (tid & 15) * 4;
        const float4 bv = *reinterpret_cast<const float4*>(
            B + (size_t)(k0 + br) * HDIM + c0 + bc);
        Bs[br][bc] = bv.x; Bs[br][bc + 1] = bv.y;
        Bs[br][bc + 2] = bv.z; Bs[br][bc + 3] = bv.w;
        __syncthreads();
        #pragma unroll
        for (int kk = 0; kk < 16; ++kk) {
            float a[4], b[4];
            #pragma unroll
            for (int i2 = 0; i2 < 4; ++i2) a[i2] = As[ty * 4 + i2][kk];
            #pragma unroll
            for (int j2 = 0; j2 < 4; ++j2) b[j2] = Bs[kk][tx * 4 + j2];
            #pragma unroll
            for (int i2 = 0; i2 < 4; ++i2)
                #pragma unroll
                for (int j2 = 0; j2 < 4; ++j2)
                    acc[i2][j2] = fmaf(a[i2], b[j2], acc[i2][j2]);
        }
        __syncthreads();
    }
    #pragma unroll
    for (int i2 = 0; i2 < 4; ++i2)
        #pragma unroll
        for (int j2 = 0; j2 < 4; ++j2)
            C[(size_t)(r0 + ty * 4 + i2) * HDIM + c0 + tx * 4 + j2] = acc[i2][j2];
}

// ---------------------------- persistent kernel -----------------------------
__global__ __launch_bounds__(BLK, 1)
void ode_rnn_persistent(
    const float* __restrict__ t,    const float* __restrict__ x,
    const float* __restrict__ W_in, const float* __restrict__ b_in,
    const float* __restrict__ W_h,  const float* __restrict__ b_h,
    const float* __restrict__ W_h2, const float* __restrict__ b_h2,
    const float* __restrict__ W_f1, const float* __restrict__ b_f1,
    const float* __restrict__ b_f2,
    const float* __restrict__ W_dec, const float* __restrict__ b_dec,
    const float* __restrict__ Mw,   const float* __restrict__ Pw,
    float* __restrict__ out,
    u64* QA, u64* QB, u64* QC, u64* QD)
{
    __shared__ __align__(16) float lds[HDIM];
    const int tid = threadIdx.x;
    const int wg  = blockIdx.x;
    const int seg = tid & 15;                 // 16 lanes per row
    const int row = wg * 16 + (tid >> 4);     // owned row

    // Poll full vector at epoch `tag` into LDS; all 4 owned slots polled
    // concurrently (one fabric round trip per sweep, not four).
    auto stage = [&](u64* q, u32 tag) {
        __syncthreads();
        const int i0 = tid, i1 = tid + 256, i2 = tid + 512, i3 = tid + 768;
        u64 v0, v1, v2, v3;
        for (;;) {
            v0 = aload(q + i0); v1 = aload(q + i1);
            v2 = aload(q + i2); v3 = aload(q + i3);
            const bool ok = ((u32)(v0 >> 32) == tag) & ((u32)(v1 >> 32) == tag) &
                            ((u32)(v2 >> 32) == tag) & ((u32)(v3 >> 32) == tag);
            if (ok) break;
        }
        lds[i0] = __uint_as_float((u32)v0); lds[i1] = __uint_as_float((u32)v1);
        lds[i2] = __uint_as_float((u32)v2); lds[i3] = __uint_as_float((u32)v3);
        __syncthreads();
    };

    auto pref16 = [&](float4* w, const float* Wbase) {
        const float4* p = reinterpret_cast<const float4*>(Wbase + (size_t)row * HDIM);
        #pragma unroll
        for (int j = 0; j < 16; ++j) w[j] = p[j * 16 + seg];
    };
    auto dot16 = [&](const float4* w) {
        float a = 0.f;
        #pragma unroll
        for (int j = 0; j < 16; ++j) {
            const float4 v = *reinterpret_cast<const float4*>(lds + j * 64 + seg * 4);
            a = fmaf(w[j].x, v.x, a); a = fmaf(w[j].y, v.y, a);
            a = fmaf(w[j].z, v.z, a); a = fmaf(w[j].w, v.w, a);
        }
        return a;
    };
    auto reduce16 = [&](float a) {
        #pragma unroll
        for (int off = 8; off; off >>= 1) a += __shfl_down(a, off, 16);
        return a;
    };

    const float bf1_r = b_f1[row];
    const float bih_r = b_in[row] + b_h[row];
    const float bh2_r = b_h2[row];

    // c1 = (W_f1 @ b_f2)[row], c2 = (W_h @ b_f2)[row]  — once, off critical path
    float c1_own, c2_own;
    {
        #pragma unroll
        for (int k = 0; k < 4; ++k) lds[tid + k * 256] = b_f2[tid + k * 256];
        __syncthreads();
        float4 w[16];
        pref16(w, W_f1); c1_own = reduce16(dot16(w));
        pref16(w, W_h);  c2_own = reduce16(dot16(w));
    }

    float z_own = bf1_r;     // z0 = W_f1 * 0 + b_f1
    float y_own = 0.f;       // y0 = W_h * 0
    u32 eA = 0, eB = 0, eC = 0, eD = 0;
    float4 wa[16], wb[16];
    float4 xr[8];

    #pragma unroll 1
    for (int i = 1; i < TSTEPS; ++i) {
        const float dt = (t[i] - t[i - 1]) * 0.25f;

        // ---- phase 1: publish u1 -> QA; consume: z,y += dt(M/P u1 + c)
        ++eA;
        if (seg == 0) astore(&QA[row], pack(eA, tanhf(z_own)));
        float4 wir[8];                         // W_in @ x_i: loads hide under poll
        {
            const float4* xp = reinterpret_cast<const float4*>(x + (size_t)i * INP);
            const float4* wp = reinterpret_cast<const float4*>(W_in + (size_t)row * INP);
            #pragma unroll
            for (int j = 0; j < 8; ++j) { xr[j] = xp[j * 16 + seg]; wir[j] = wp[j * 16 + seg]; }
        }
        pref16(wa, Mw); pref16(wb, Pw);
        stage(QA, eA);
        float winx;
        {
            float a_ = 0.f;
            #pragma unroll
            for (int j = 0; j < 8; ++j) {
                a_ = fmaf(wir[j].x, xr[j].x, a_); a_ = fmaf(wir[j].y, xr[j].y, a_);
                a_ = fmaf(wir[j].z, xr[j].z, a_); a_ = fmaf(wir[j].w, xr[j].w, a_);
            }
            winx = reduce16(a_);
        }
        {
            const float md = reduce16(dot16(wa));
            const float pd = reduce16(dot16(wb));
            if (seg == 0) { z_own = fmaf(dt, md + c1_own, z_own);
                            y_own = fmaf(dt, pd + c2_own, y_own); }
        }

        // ---- phase 2: publish u2 -> QB
        ++eB;
        if (seg == 0) astore(&QB[row], pack(eB, tanhf(z_own)));
        pref16(wa, Mw); pref16(wb, Pw);
        stage(QB, eB);
        {
            const float md = reduce16(dot16(wa));
            const float pd = reduce16(dot16(wb));
            if (seg == 0) { z_own = fmaf(dt, md + c1_own, z_own);
                            y_own = fmaf(dt, pd + c2_own, y_own); }
        }

        // ---- phase 3: publish u3 -> QA
        ++eA;
        if (seg == 0) astore(&QA[row], pack(eA, tanhf(z_own)));
        pref16(wa, Mw); pref16(wb, Pw);
        stage(QA, eA);
        {
            const float md = reduce16(dot16(wa));
            const float pd = reduce16(dot16(wb));
            if (seg == 0) { z_own = fmaf(dt, md + c1_own, z_own);
                            y_own = fmaf(dt, pd + c2_own, y_own); }
        }

        // ---- phase 4: publish u4 -> QB; consume: y4 only (z4 dead), then a
        ++eB;
        if (seg == 0) astore(&QB[row], pack(eB, tanhf(z_own)));
        pref16(wb, Pw);
        stage(QB, eB);
        float a_val = 0.f;
        {
            const float pd = reduce16(dot16(wb));
            if (seg == 0) {
                const float y4 = fmaf(dt, pd + c2_own, y_own);
                a_val = tanhf(y4 + winx + bih_r);
            }
        }

        // ---- phase 5: publish a -> QC; consume: h' = tanh(W_h2 a + b_h2)
        ++eC;
        if (seg == 0) astore(&QC[row], pack(eC, a_val));
        pref16(wa, W_h2);
        stage(QC, eC);
        float h_new = 0.f;
        {
            const float hd = reduce16(dot16(wa));
            if (seg == 0) h_new = tanhf(hd + bh2_r);
        }

        // ---- phase 6: publish h' -> QD; consume: z0' = W_f1 h' + b_f1, y0' = W_h h'
        ++eD;
        if (seg == 0) astore(&QD[row], pack(eD, h_new));
        pref16(wa, W_f1);
        stage(QD, eD);
        {
            const float zd = reduce16(dot16(wa));
            pref16(wb, W_h);
            const float yd = reduce16(dot16(wb));
            if (seg == 0) { z_own = zd + bf1_r; y_own = yd; }
        }
    }

    // ---- decoder: lds still holds h_T from the last phase-6 stage
    {
        const int rl = tid >> 6, s2 = tid & 63;
        const int orow = wg * 4 + rl;
        const float4* wd = reinterpret_cast<const float4*>(W_dec + (size_t)orow * HDIM);
        float acc = 0.f;
        #pragma unroll
        for (int j = 0; j < 4; ++j) {
            const float4 w = wd[j * 64 + s2];
            const float4 v = *reinterpret_cast<const float4*>(lds + j * 256 + s2 * 4);
            acc = fmaf(w.x, v.x, acc); acc = fmaf(w.y, v.y, acc);
            acc = fmaf(w.z, v.z, acc); acc = fmaf(w.w, v.w, acc);
        }
        #pragma unroll
        for (int off = 32; off; off >>= 1) acc += __shfl_down(acc, off, 64);
        if (s2 == 0) out[orow] = acc + b_dec[orow];
    }
}

extern "C" void kernel_launch(void* const* d_in, const int* in_sizes, int n_in,
                              void* d_out, int out_size, void* d_ws, size_t ws_size,
                              hipStream_t stream) {
    const float* t     = (const float*)d_in[0];
    const float* x     = (const float*)d_in[1];
    const float* W_in  = (const float*)d_in[2];
    const float* b_in  = (const float*)d_in[3];
    const float* W_h   = (const float*)d_in[4];
    const float* b_h   = (const float*)d_in[5];
    const float* W_h2  = (const float*)d_in[6];
    const float* b_h2  = (const float*)d_in[7];
    const float* W_f1  = (const float*)d_in[8];
    const float* b_f1  = (const float*)d_in[9];
    const float* W_f2  = (const float*)d_in[10];
    const float* b_f2  = (const float*)d_in[11];
    const float* W_dec = (const float*)d_in[12];
    const float* b_dec = (const float*)d_in[13];
    float* out = (float*)d_out;

    // ws layout: M (4MB) | P (4MB) | QA,QB,QC,QD (4 x 8KB)
    unsigned char* ws = (unsigned char*)d_ws;
    float* Mw = (float*)(ws);
    float* Pw = (float*)(ws + (size_t)4 * 1024 * 1024);
    u64*   QA = (u64*)(ws + (size_t)8 * 1024 * 1024);
    u64*   QB = QA + HDIM;
    u64*   QC = QB + HDIM;
    u64*   QD = QC + HDIM;

    // precompute M = W_f1 @ W_f2, P = W_h @ W_f2 (every call; deterministic)
    mm1024<<<dim3(16, 16), 256, 0, stream>>>(W_f1, W_f2, Mw);
    mm1024<<<dim3(16, 16), 256, 0, stream>>>(W_h,  W_f2, Pw);

    // reset epoch tags to 0 (first expected tag is 1); every call
    hipMemsetAsync(ws + (size_t)8 * 1024 * 1024, 0, 4 * HDIM * sizeof(u64), stream);

    ode_rnn_persistent<<<dim3(NWG), dim3(BLK), 0, stream>>>(
        t, x, W_in, b_in, W_h, b_h, W_h2, b_h2, W_f1, b_f1, b_f2,
        W_dec, b_dec, Mw, Pw, out, QA, QB, QC, QD);
}